// Round 3
// baseline (2199.943 us; speedup 1.0000x reference)
//
#include <hip/hip_runtime.h>
#include <hip/hip_bf16.h>

// y = x @ W_eff^T with W_eff = W_base + 0.5*sum(alpha_i * B_i A_i)
// Split-bf16 (Ootomo) GEMM: y = xh@Wh^T + xh@Wl^T + xl@Wh^T
// GEMM: 256x256 tile, BK=64, 8-phase pipelined schedule (counted lgkm/vmcnt),
// XOR-swizzled LDS staged via global_load_lds w/ pre-swizzled global source.

typedef __attribute__((ext_vector_type(8))) short bf16x8;
typedef __attribute__((ext_vector_type(4))) float f32x4;
typedef __attribute__((ext_vector_type(8))) unsigned short u16x8;

#define GLOBAL_LOAD_LDS16(gp, lp)                                                   \
  __builtin_amdgcn_global_load_lds(                                                 \
      (const __attribute__((address_space(1))) unsigned int*)(gp),                  \
      (__attribute__((address_space(3))) unsigned int*)(lp), 16, 0, 0)

__device__ inline unsigned short bf16_rne(float f) {
  unsigned int u = __builtin_bit_cast(unsigned int, f);
  u += 0x7fffu + ((u >> 16) & 1u);
  return (unsigned short)(u >> 16);
}
__device__ inline float bf16_to_f(unsigned short h) {
  unsigned int u = ((unsigned int)h) << 16;
  return __builtin_bit_cast(float, u);
}

// ---------------- kernel 1: split x into hi/lo bf16 ----------------
__global__ __launch_bounds__(256) void split_x(const float* __restrict__ x,
                                               unsigned short* __restrict__ xh,
                                               unsigned short* __restrict__ xl) {
  size_t i = ((size_t)blockIdx.x * 256 + threadIdx.x) * 8;
  float4 v0 = *(const float4*)(x + i);
  float4 v1 = *(const float4*)(x + i + 4);
  float f[8] = {v0.x, v0.y, v0.z, v0.w, v1.x, v1.y, v1.z, v1.w};
  u16x8 vh, vl;
#pragma unroll
  for (int j = 0; j < 8; ++j) {
    unsigned short h = bf16_rne(f[j]);
    vh[j] = h;
    vl[j] = bf16_rne(f[j] - bf16_to_f(h));
  }
  *(u16x8*)(xh + i) = vh;
  *(u16x8*)(xl + i) = vl;
}

// ---------------- kernel 2: fold adapters into W_eff, split hi/lo ----------------
__global__ __launch_bounds__(256) void fold_w(
    const float* __restrict__ W, const float* __restrict__ A8,
    const float* __restrict__ B8, const float* __restrict__ A16,
    const float* __restrict__ B16, const float* __restrict__ A32,
    const float* __restrict__ B32, const float* __restrict__ alphas,
    unsigned short* __restrict__ Wh, unsigned short* __restrict__ Wl) {
  __shared__ float Bc[16][56];
  const int tid = threadIdx.x;
  const int o0 = blockIdx.x * 16;
  const int d0 = blockIdx.y * 2048;
  const float c0 = 0.5f * alphas[0], c1 = 0.5f * alphas[1], c2 = 0.5f * alphas[2];
  for (int t = tid; t < 16 * 56; t += 256) {
    int oi = t / 56, r = t % 56, o = o0 + oi;
    float v;
    if (r < 8)
      v = c0 * B8[o * 8 + r];
    else if (r < 24)
      v = c1 * B16[o * 16 + (r - 8)];
    else
      v = c2 * B32[o * 32 + (r - 24)];
    Bc[oi][r] = v;
  }
  __syncthreads();
  for (int c = 0; c < 8; ++c) {
    const int d = d0 + c * 256 + tid;
    float a[56];
#pragma unroll
    for (int r = 0; r < 8; ++r) a[r] = A8[r * 4096 + d];
#pragma unroll
    for (int r = 0; r < 16; ++r) a[8 + r] = A16[r * 4096 + d];
#pragma unroll
    for (int r = 0; r < 32; ++r) a[24 + r] = A32[r * 4096 + d];
#pragma unroll 4
    for (int oi = 0; oi < 16; ++oi) {
      float w = W[(size_t)(o0 + oi) * 4096 + d];
#pragma unroll
      for (int r = 0; r < 56; ++r) w = fmaf(Bc[oi][r], a[r], w);
      unsigned short h = bf16_rne(w);
      Wh[(size_t)(o0 + oi) * 4096 + d] = h;
      Wl[(size_t)(o0 + oi) * 4096 + d] = bf16_rne(w - bf16_to_f(h));
    }
  }
}

// ---------------- kernel 3: 256^2-tile 8-phase split-bf16 GEMM ----------------
// C[8192][4096] = Xh@Wh^T + Xh@Wl^T + Xl@Wh^T ; flat tile stream t=0..191
//   pass 0: t 0..63   A=Xh B=Wh ; pass 1: t 64..127 A=Xh B=Wl ; pass 2: A=Xl B=Wh
// 8 waves (2M x 4N); wave out 128x64 = 8x4 frags of 16x16 (mfma 16x16x32 bf16).
// LDS: 2 buf x {A,B} x 2 halves x [128][64] bf16 = 128 KiB, XOR swizzle
// byte ^= ((row&7)<<4) applied via pre-swizzled global source (rule #21).

#define BAR __builtin_amdgcn_s_barrier()
#define P1 __builtin_amdgcn_s_setprio(1)
#define P0 __builtin_amdgcn_s_setprio(0)
#define SCHB __builtin_amdgcn_sched_barrier(0)
#define LGKM(N) asm volatile("s_waitcnt lgkmcnt(" #N ")" ::: "memory")
#define VMC(N) asm volatile("s_waitcnt vmcnt(" #N ")" ::: "memory")

__global__ __launch_bounds__(512) void gemm8ph(const unsigned short* __restrict__ Xh,
                                               const unsigned short* __restrict__ Xl,
                                               const unsigned short* __restrict__ Wh,
                                               const unsigned short* __restrict__ Wl,
                                               float* __restrict__ C) {
  __shared__ __align__(16) unsigned short lds[65536];  // 128 KiB

  const int tid = threadIdx.x;
  const int lane = tid & 63;
  const int wid = tid >> 6;
  const int wm = wid >> 2, wn = wid & 3;

  // XCD-aware swizzle (nwg=512, 512%8==0 -> simple form is bijective)
  const int bid = blockIdx.x;
  const int swz = (bid & 7) * 64 + (bid >> 3);
  const int m0 = (swz >> 4) * 256;   // 32 m-blocks
  const int n0 = (swz & 15) * 256;   // 16 n-blocks

  // ---- staging geometry (pre-swizzled global source, linear LDS dest) ----
  const int r8 = lane >> 3;                 // row within 8-row group
  const int lsl = (lane & 7) ^ r8;          // swizzled 16B slot in source
  const size_t sA = (size_t)(m0 + wid * 8 + r8) * 4096 + (size_t)lsl * 8;
  const size_t sB = (size_t)(n0 + wid * 8 + r8) * 4096 + (size_t)lsl * 8;

  // ---- LDS read geometry ----
  const int aB = wm * 8192 + (lane & 15) * 64;
  const int bB = 16384 + (wn >> 1) * 8192 + (wn & 1) * 4096 + (lane & 15) * 64;
  int colS[2];
#pragma unroll
  for (int ks = 0; ks < 2; ++ks)
    colS[ks] = (ks * 32 + ((lane >> 4) * 8)) ^ ((lane & 7) << 3);

#define LDA(BUF, MI, KS) (*(const bf16x8*)&lds[((BUF) << 15) + aB + ((MI) << 10) + colS[KS]])
#define LDB(BUF, NI, KS) (*(const bf16x8*)&lds[((BUF) << 15) + bB + ((NI) << 10) + colS[KS]])

#define STG(MAT, T, H)                                                                   \
  do {                                                                                   \
    const unsigned short* __restrict__ gp =                                              \
        (MAT) ? (((unsigned)((T)-64) < 64u) ? Wl : Wh) : (((T) >= 128) ? Xl : Xh);       \
    const size_t go = ((MAT) ? sB : sA) + (size_t)(H)*524288 + (size_t)(((T)&63) * 64);  \
    unsigned short* lp = &lds[(((T)&1) << 15) + ((MAT) << 14) + ((H) << 13) + (wid << 9)]; \
    GLOBAL_LOAD_LDS16(gp + go, lp);                                                      \
    GLOBAL_LOAD_LDS16(gp + go + 262144, lp + 4096);                                      \
  } while (0)

  bf16x8 af[8][2];
  bf16x8 bf_[4][2];
  f32x4 acc[8][4];
#pragma unroll
  for (int mi = 0; mi < 8; ++mi)
#pragma unroll
    for (int ni = 0; ni < 4; ++ni) acc[mi][ni] = (f32x4){0.f, 0.f, 0.f, 0.f};

#define RD_Q1(BUF)                                                \
  do {                                                            \
    _Pragma("unroll") for (int q = 0; q < 4; ++q)                 \
        _Pragma("unroll") for (int ks = 0; ks < 2; ++ks)          \
            af[q][ks] = LDA(BUF, q, ks);                          \
    _Pragma("unroll") for (int q = 0; q < 2; ++q)                 \
        _Pragma("unroll") for (int ks = 0; ks < 2; ++ks)          \
            bf_[q][ks] = LDB(BUF, q, ks);                         \
  } while (0)
#define RD_Q2(BUF)                                                \
  do {                                                            \
    _Pragma("unroll") for (int q = 2; q < 4; ++q)                 \
        _Pragma("unroll") for (int ks = 0; ks < 2; ++ks)          \
            bf_[q][ks] = LDB(BUF, q, ks);                         \
  } while (0)
#define RD_Q3(BUF)                                                \
  do {                                                            \
    _Pragma("unroll") for (int q = 4; q < 8; ++q)                 \
        _Pragma("unroll") for (int ks = 0; ks < 2; ++ks)          \
            af[q][ks] = LDA(BUF, q, ks);                          \
  } while (0)

#define MFMAQ(MQ, NQ)                                                                    \
  do {                                                                                   \
    _Pragma("unroll") for (int mi = (MQ)*4; mi < (MQ)*4 + 4; ++mi)                       \
        _Pragma("unroll") for (int ni = (NQ)*2; ni < (NQ)*2 + 2; ++ni)                   \
            _Pragma("unroll") for (int ks = 0; ks < 2; ++ks)                             \
                acc[mi][ni] = __builtin_amdgcn_mfma_f32_16x16x32_bf16(                   \
                    af[mi][ks], bf_[ni][ks], acc[mi][ni], 0, 0, 0);                      \
  } while (0)

  // ---------------- prologue ----------------
  STG(0, 0, 0);  // A(0,0)
  STG(0, 0, 1);  // A(0,1)
  STG(1, 0, 0);  // B(0,0)
  STG(1, 0, 1);  // B(0,1)
  STG(1, 1, 0);  // B(1,0)
  STG(0, 1, 0);  // A(1,0)
  VMC(4);        // tile 0 landed (B(1,0)/A(1,0) may be in flight)
  BAR;
  RD_Q1(0);      // tile 0 quadrant-1 frags (12 ds_reads, drained at ph1 LGKM(4))

  // ---------------- main loop: 95 iterations, tiles 0..189 ----------------
#pragma clang loop unroll(disable)
  for (int it = 0; it < 95; ++it) {
    const int O = 2 * it + 1, E2 = 2 * it + 2, O2 = 2 * it + 3;
    // ph1: MFMA Q_E(0,0); reads for Q_E(0,1); stage B(O,1)
    RD_Q2(0);
    STG(1, O, 1);
    BAR; LGKM(4); SCHB; P1; MFMAQ(0, 0); P0; BAR;
    // ph2
    RD_Q3(0);
    STG(0, O, 1);
    BAR; LGKM(8); SCHB; P1; MFMAQ(0, 1); P0; BAR;
    // ph3  (vmcnt(2) before barrier -> tile O landed & published)
    STG(1, E2, 0);
    BAR; LGKM(0); SCHB; P1; MFMAQ(1, 0); P0; VMC(2); BAR;
    // ph4: reads tile O quadrant-1
    RD_Q1(1);
    STG(0, E2, 0);
    BAR; LGKM(12); SCHB; P1; MFMAQ(1, 1); P0; BAR;
    // ph5
    RD_Q2(1);
    STG(1, E2, 1);
    BAR; LGKM(4); SCHB; P1; MFMAQ(0, 0); P0; BAR;
    // ph6
    RD_Q3(1);
    STG(0, E2, 1);
    BAR; LGKM(8); SCHB; P1; MFMAQ(0, 1); P0; BAR;
    // ph7  (vmcnt(2) -> tile E' landed & published)
    STG(1, O2, 0);
    BAR; LGKM(0); SCHB; P1; MFMAQ(1, 0); P0; VMC(2); BAR;
    // ph8: reads tile E' quadrant-1
    RD_Q1(0);
    STG(0, O2, 0);
    BAR; LGKM(12); SCHB; P1; MFMAQ(1, 1); P0; BAR;
  }

  // ---------------- epilogue: tiles 190 (buf0), 191 (buf1) ----------------
  RD_Q2(0); STG(1, 191, 1);
  BAR; LGKM(4); SCHB; P1; MFMAQ(0, 0); P0; BAR;
  RD_Q3(0); STG(0, 191, 1);
  BAR; LGKM(8); SCHB; P1; MFMAQ(0, 1); P0; BAR;
  BAR; LGKM(0); SCHB; P1; MFMAQ(1, 0); P0; VMC(0); BAR;
  RD_Q1(1);
  BAR; LGKM(12); SCHB; P1; MFMAQ(1, 1); P0; BAR;
  RD_Q2(1);
  BAR; LGKM(4); SCHB; P1; MFMAQ(0, 0); P0; BAR;
  RD_Q3(1);
  BAR; LGKM(8); SCHB; P1; MFMAQ(0, 1); P0; BAR;
  BAR; LGKM(0); SCHB; P1; MFMAQ(1, 0); P0; BAR;
  LGKM(0); P1; MFMAQ(1, 1); P0;

  // ---------------- C write: col = lane&15, row = (lane>>4)*4 + reg ----------------
#pragma unroll
  for (int mi = 0; mi < 8; ++mi)
#pragma unroll
    for (int ni = 0; ni < 4; ++ni) {
      const int row = m0 + wm * 128 + mi * 16 + (lane >> 4) * 4;
      const int col = n0 + wn * 64 + ni * 16 + (lane & 15);
      float* cp = C + (size_t)row * 4096 + col;
      cp[0] = acc[mi][ni][0];
      cp[4096] = acc[mi][ni][1];
      cp[2 * 4096] = acc[mi][ni][2];
      cp[3 * 4096] = acc[mi][ni][3];
    }
}

extern "C" void kernel_launch(void* const* d_in, const int* in_sizes, int n_in,
                              void* d_out, int out_size, void* d_ws, size_t ws_size,
                              hipStream_t stream) {
  const float* x = (const float*)d_in[0];
  const float* Wb = (const float*)d_in[1];
  const float* A8 = (const float*)d_in[2];
  const float* B8 = (const float*)d_in[3];
  const float* A16 = (const float*)d_in[4];
  const float* B16 = (const float*)d_in[5];
  const float* A32 = (const float*)d_in[6];
  const float* B32 = (const float*)d_in[7];
  const float* al = (const float*)d_in[8];
  float* out = (float*)d_out;

  char* ws = (char*)d_ws;
  unsigned short* xh = (unsigned short*)(ws);
  unsigned short* xl = (unsigned short*)(ws + 67108864);   // 64 MB
  unsigned short* wh = (unsigned short*)(ws + 134217728);  // 128 MB
  unsigned short* wl = (unsigned short*)(ws + 167772160);  // 160 MB

  split_x<<<16384, 256, 0, stream>>>(x, xh, xl);
  fold_w<<<dim3(256, 2), 256, 0, stream>>>(Wb, A8, B8, A16, B16, A32, B32, al, wh, wl);
  gemm8ph<<<512, 512, 0, stream>>>(xh, xl, wh, wl, out);
}